// Round 1
// baseline (1067.832 us; speedup 1.0000x reference)
//
#include <hip/hip_runtime.h>
#include <hip/hip_fp16.h>

#define BATCH 16
#define NROW 1024
#define MCOL 1024
#define DFEAT 128
#define NDIAG 2047          // NROW + MCOL - 1
#define BIGV 1e10f

// ---------------------------------------------------------------------------
// Kernel 1: inverse norms, one 64-lane wave per row (128 floats -> float2/lane)
// ---------------------------------------------------------------------------
__global__ __launch_bounds__(256) void norm_kernel(
    const float* __restrict__ x, const float* __restrict__ y,
    float* __restrict__ invnx, float* __restrict__ invny) {
  int row = blockIdx.x * 4 + (threadIdx.x >> 6);
  int lane = threadIdx.x & 63;
  const float* src;
  float* dst;
  if (row < BATCH * NROW) {
    src = x + (size_t)row * DFEAT;
    dst = invnx + row;
  } else {
    int r2 = row - BATCH * NROW;
    src = y + (size_t)r2 * DFEAT;
    dst = invny + r2;
  }
  float2 v = *(const float2*)(src + lane * 2);
  float s = v.x * v.x + v.y * v.y;
  #pragma unroll
  for (int o = 32; o > 0; o >>= 1) s += __shfl_down(s, o, 64);
  if (lane == 0) *dst = 1.0f / (sqrtf(s) + 1e-8f);
}

// ---------------------------------------------------------------------------
// Kernel 2: D tile GEMM (64x64 per block, 4x4 per thread, K chunked 2x64),
// epilogue writes fp16 D in anti-diagonal-major layout Dd[b][s0][i0].
// ---------------------------------------------------------------------------
#define TP 68               // LDS pitch for 64-float K-chunk (+4 pad: 2-way max)

__global__ __launch_bounds__(256) void dist_kernel(
    const float* __restrict__ x, const float* __restrict__ y,
    const float* __restrict__ invnx, const float* __restrict__ invny,
    __half* __restrict__ Dd) {
  __shared__ __align__(16) float smem[2 * 64 * TP];   // 34.8 KB
  float* xs = smem;
  float* ys = smem + 64 * TP;

  int b = blockIdx.z, ti = blockIdx.y, tj = blockIdx.x;
  int I0 = ti * 64, J0 = tj * 64;
  const float* xb = x + ((size_t)b * NROW + I0) * DFEAT;
  const float* yb = y + ((size_t)b * MCOL + J0) * DFEAT;
  int tid = threadIdx.x;
  int tx = tid & 15, ty = tid >> 4;

  float acc[4][4] = {};

  for (int c0 = 0; c0 < DFEAT; c0 += 64) {
    if (c0) __syncthreads();
    // stage 64 rows x 64 k of x and y (float4, coalesced)
    #pragma unroll
    for (int it = 0; it < 4; ++it) {
      int f = (tid + it * 256) * 4;       // 0..4092
      int row = f >> 6, k = f & 63;
      *(float4*)&xs[row * TP + k] = *(const float4*)&xb[row * DFEAT + c0 + k];
      *(float4*)&ys[row * TP + k] = *(const float4*)&yb[row * DFEAT + c0 + k];
    }
    __syncthreads();
    #pragma unroll
    for (int kb = 0; kb < 64; kb += 4) {
      float4 xv[4], yv[4];
      #pragma unroll
      for (int r = 0; r < 4; ++r) xv[r] = *(float4*)&xs[(ty + 16 * r) * TP + kb];
      #pragma unroll
      for (int c = 0; c < 4; ++c) yv[c] = *(float4*)&ys[(tx + 16 * c) * TP + kb];
      #pragma unroll
      for (int r = 0; r < 4; ++r)
        #pragma unroll
        for (int c = 0; c < 4; ++c)
          acc[r][c] += xv[r].x * yv[c].x + xv[r].y * yv[c].y +
                       xv[r].z * yv[c].z + xv[r].w * yv[c].w;
    }
  }

  float inx[4], iny[4];
  #pragma unroll
  for (int r = 0; r < 4; ++r) inx[r] = invnx[b * NROW + I0 + ty + 16 * r];
  #pragma unroll
  for (int c = 0; c < 4; ++c) iny[c] = invny[b * MCOL + J0 + tx + 16 * c];

  __syncthreads();
  // skewed fp16 restage: tile[il][(il+jl)&63], pitch 65
  __half* tile = (__half*)smem;
  #pragma unroll
  for (int r = 0; r < 4; ++r) {
    int il = ty + 16 * r;
    #pragma unroll
    for (int c = 0; c < 4; ++c) {
      int jl = tx + 16 * c;
      float d = 1.0f - acc[r][c] * inx[r] * iny[c];
      tile[il * 65 + ((il + jl) & 63)] = __float2half(d);
    }
  }
  __syncthreads();

  // write 127 tile anti-diagonals; 4 diag-groups of 64 lanes
  int g = tid >> 6, l = tid & 63;
  size_t baseRow = ((size_t)b * NDIAG + (I0 + J0)) * (size_t)NROW + I0;
  for (int dbase = 0; dbase < 127; dbase += 4) {
    int d = dbase + g;
    if (d <= 126) {
      int ilo = d > 63 ? d - 63 : 0;
      int len = (d < 63 ? d : 126 - d) + 1;   // min(d+1, 127-d)
      if (l < len) {
        int il = ilo + l;
        Dd[baseRow + (size_t)d * NROW + il] = tile[il * 65 + (d & 63)];
      }
    }
  }
}

// ---------------------------------------------------------------------------
// Kernel 3: soft-DTW DP. 1 block per batch, thread t = row i = t+1.
// Registers hold R[i][j-1] (ra) and R[i][j-2-ish] (rb); neighbor values via
// shfl_up; wave boundaries via double-buffered LDS; 1 barrier per diagonal.
// ---------------------------------------------------------------------------
__global__ __launch_bounds__(1024) void dtw_kernel(
    const __half* __restrict__ Dd, float* __restrict__ out) {
  int b = blockIdx.x;
  int t = threadIdx.x;                 // row i = t+1
  int lane = t & 63, w = t >> 6;
  __shared__ float bndA[2][16], bndB[2][16];
  if (t < 16) {
    bndA[0][t] = BIGV; bndA[1][t] = BIGV;
    bndB[0][t] = BIGV; bndB[1][t] = BIGV;
  }
  float ra = BIGV, rb = BIGV;
  const __half* Db = Dd + (size_t)b * NDIAG * NROW;
  float dcur = __half2float(Db[t]);    // diagonal s=2 lives in row 0
  __syncthreads();

  const float L2E = 1.4426950408889634f;
  const float LN2 = 0.6931471805599453f;

  for (int s = 2; s <= NROW + MCOL; ++s) {
    float dnext = (s < NROW + MCOL) ? __half2float(Db[(size_t)(s - 1) * NROW + t]) : 0.f;
    float na = __shfl_up(ra, 1, 64);   // R[i-1][j]
    float nb = __shfl_up(rb, 1, 64);   // R[i-1][j-1]
    if (lane == 0) {
      if (w == 0) { na = BIGV; nb = (s == 2) ? 0.0f : BIGV; }
      else        { na = bndA[(s - 1) & 1][w - 1]; nb = bndB[(s - 1) & 1][w - 1]; }
    }
    float m = fminf(fminf(na, nb), ra);
    float e0 = exp2f((m - nb) * L2E);
    float e1 = exp2f((m - na) * L2E);
    float e2 = exp2f((m - ra) * L2E);
    float rnew = dcur + m - LN2 * log2f(e0 + e1 + e2);
    bool act = (s >= t + 2) && (s <= t + 1 + MCOL);
    rb = ra;
    ra = act ? rnew : ra;              // before activation ra stays BIGV
    if (lane == 63) { bndA[s & 1][w] = ra; bndB[s & 1][w] = rb; }
    dcur = dnext;
    __syncthreads();
  }
  if (t == NROW - 1) out[b] = ra;      // R[N][M]
}

// ---------------------------------------------------------------------------
extern "C" void kernel_launch(void* const* d_in, const int* in_sizes, int n_in,
                              void* d_out, int out_size, void* d_ws, size_t ws_size,
                              hipStream_t stream) {
  const float* x = (const float*)d_in[0];
  const float* y = (const float*)d_in[1];
  float* out = (float*)d_out;

  char* ws = (char*)d_ws;
  __half* Dd = (__half*)ws;
  size_t dd_bytes = (size_t)BATCH * NDIAG * NROW * sizeof(__half);  // ~67 MB
  float* invnx = (float*)(ws + dd_bytes);
  float* invny = invnx + BATCH * NROW;

  // 1) inverse norms: 2*16*1024 rows, 4 rows (waves) per block
  norm_kernel<<<(2 * BATCH * NROW) / 4, 256, 0, stream>>>(x, y, invnx, invny);

  // 2) distance matrix in anti-diagonal fp16 layout
  dist_kernel<<<dim3(MCOL / 64, NROW / 64, BATCH), 256, 0, stream>>>(
      x, y, invnx, invny, Dd);

  // 3) wavefront DP
  dtw_kernel<<<BATCH, 1024, 0, stream>>>(Dd, out);
}

// Round 5
// 477.654 us; speedup vs baseline: 2.2356x; 2.2356x over previous
//
#include <hip/hip_runtime.h>
#include <hip/hip_fp16.h>

#define BATCH 16
#define NROW 1024
#define MCOL 1024
#define DFEAT 128

// DP blocking
#define T_DP 256            // threads per block (4 waves)
#define R_DP 4              // rows per thread
#define C_DP 8              // columns per phase chunk
#define NCH (MCOL / C_DP)   // 128 chunks along j
#define NPH (NCH + T_DP - 1) // 383 phases

#define L2E 1.4426950408889634f
#define LN2 0.6931471805599453f

// ---------------------------------------------------------------------------
// Kernel 1: inverse norms, one 64-lane wave per row
// ---------------------------------------------------------------------------
__global__ __launch_bounds__(256) void norm_kernel(
    const float* __restrict__ x, const float* __restrict__ y,
    float* __restrict__ invnx, float* __restrict__ invny) {
  int row = blockIdx.x * 4 + (threadIdx.x >> 6);
  int lane = threadIdx.x & 63;
  const float* src;
  float* dst;
  if (row < BATCH * NROW) {
    src = x + (size_t)row * DFEAT;
    dst = invnx + row;
  } else {
    int r2 = row - BATCH * NROW;
    src = y + (size_t)r2 * DFEAT;
    dst = invny + r2;
  }
  float2 v = *(const float2*)(src + lane * 2);
  float s = v.x * v.x + v.y * v.y;
  #pragma unroll
  for (int o = 32; o > 0; o >>= 1) s += __shfl_down(s, o, 64);
  if (lane == 0) *dst = 1.0f / (sqrtf(s) + 1e-8f);
}

// ---------------------------------------------------------------------------
// Kernel 2: distance GEMM; epilogue stores expd = exp(-D) row-major fp16.
// ---------------------------------------------------------------------------
#define TP 68               // LDS pitch for 64-float K-chunk

__global__ __launch_bounds__(256) void dist_kernel(
    const float* __restrict__ x, const float* __restrict__ y,
    const float* __restrict__ invnx, const float* __restrict__ invny,
    __half* __restrict__ Dexp) {
  __shared__ __align__(16) float smem[2 * 64 * TP];   // 34.8 KB
  float* xs = smem;
  float* ys = smem + 64 * TP;

  int b = blockIdx.z, ti = blockIdx.y, tj = blockIdx.x;
  int I0 = ti * 64, J0 = tj * 64;
  const float* xb = x + ((size_t)b * NROW + I0) * DFEAT;
  const float* yb = y + ((size_t)b * MCOL + J0) * DFEAT;
  int tid = threadIdx.x;
  int tx = tid & 15, ty = tid >> 4;

  float acc[4][4] = {};

  for (int c0 = 0; c0 < DFEAT; c0 += 64) {
    if (c0) __syncthreads();
    #pragma unroll
    for (int it = 0; it < 4; ++it) {
      int f = (tid + it * 256) * 4;
      int row = f >> 6, k = f & 63;
      *(float4*)&xs[row * TP + k] = *(const float4*)&xb[row * DFEAT + c0 + k];
      *(float4*)&ys[row * TP + k] = *(const float4*)&yb[row * DFEAT + c0 + k];
    }
    __syncthreads();
    #pragma unroll
    for (int kb = 0; kb < 64; kb += 4) {
      float4 xv[4], yv[4];
      #pragma unroll
      for (int r = 0; r < 4; ++r) xv[r] = *(float4*)&xs[(ty + 16 * r) * TP + kb];
      #pragma unroll
      for (int c = 0; c < 4; ++c) yv[c] = *(float4*)&ys[(tx + 16 * c) * TP + kb];
      #pragma unroll
      for (int r = 0; r < 4; ++r)
        #pragma unroll
        for (int c = 0; c < 4; ++c)
          acc[r][c] += xv[r].x * yv[c].x + xv[r].y * yv[c].y +
                       xv[r].z * yv[c].z + xv[r].w * yv[c].w;
    }
  }

  float inx[4], iny[4];
  #pragma unroll
  for (int r = 0; r < 4; ++r) inx[r] = invnx[b * NROW + I0 + ty + 16 * r];
  #pragma unroll
  for (int c = 0; c < 4; ++c) iny[c] = invny[b * MCOL + J0 + tx + 16 * c];

  __syncthreads();
  // restage exp(-d) as fp16 tile, pitch 66 halfs (dword-aligned rows)
  __half* tile = (__half*)smem;
  #pragma unroll
  for (int r = 0; r < 4; ++r) {
    int il = ty + 16 * r;
    #pragma unroll
    for (int c = 0; c < 4; ++c) {
      int jl = tx + 16 * c;
      float d = 1.0f - acc[r][c] * inx[r] * iny[c];
      float ed = exp2f(-d * L2E);
      tile[il * 66 + jl] = __float2half(ed);
    }
  }
  __syncthreads();

  // coalesced dword writes: 8 rows per pass (row = tid>>5), dword col = tid&31
  unsigned* dst32 = (unsigned*)Dexp;
  #pragma unroll
  for (int pass = 0; pass < 8; ++pass) {
    int row = pass * 8 + (tid >> 5);
    int cd = tid & 31;
    unsigned v = *(unsigned*)&tile[row * 66 + cd * 2];
    dst32[((size_t)(b * NROW + I0 + row) * MCOL + J0) / 2 + cd] = v;
  }
}

// ---------------------------------------------------------------------------
// Kernel 3: blocked exp-domain soft-DTW DP.
// Thread t owns rows (t*4..t*4+3); phase p processes chunk c = p - t of 8
// columns; skew 1 phase/thread. State E = exp(O - R) with per-lane offset O.
// Renorm invariant: E' = E * 2^-ex  requires  O' = O - ex*ln2  (sign was
// flipped in rounds 3-4 -> diverging frames -> sc overflow -> inf).
// ---------------------------------------------------------------------------
__device__ inline void unpack8(uint4 v, float* e) {
  const __half2* h = reinterpret_cast<const __half2*>(&v);
  #pragma unroll
  for (int q = 0; q < 4; ++q) {
    float2 f = __half22float2(h[q]);
    e[2 * q] = f.x;
    e[2 * q + 1] = f.y;
  }
}

__global__ __launch_bounds__(T_DP) void dtw_kernel(
    const __half* __restrict__ Dexp, float* __restrict__ out) {
  int b = blockIdx.x;
  int t = threadIdx.x;
  int lane = t & 63, w = t >> 6;

  __shared__ float bnd[2][T_DP / 64][C_DP + 2];  // [parity][wave][B(9) + O]
  if (t < 2 * (T_DP / 64) * (C_DP + 2)) ((float*)bnd)[t] = 0.0f;
  __syncthreads();

  const __half* Db = Dexp + ((size_t)b * NROW + (size_t)t * R_DP) * MCOL;

  float carry[R_DP] = {0.f, 0.f, 0.f, 0.f};
  float B[C_DP + 1] = {};
  float O = 0.0f;

  auto loadrow = [&](int r, int c) -> uint4 {
    int cc = c < 0 ? 0 : (c >= NCH ? NCH - 1 : c);
    return *reinterpret_cast<const uint4*>(Db + (size_t)r * MCOL + cc * C_DP);
  };

  uint4 cur[R_DP], nxt[R_DP];
  #pragma unroll
  for (int r = 0; r < R_DP; ++r) cur[r] = loadrow(r, 0 - t);

  for (int p = 0; p < NPH; ++p) {
    int c = p - t;
    // prefetch next phase's chunk
    #pragma unroll
    for (int r = 0; r < R_DP; ++r) nxt[r] = loadrow(r, c + 1);

    // receive up-row from neighbor (its B built last phase)
    float U[C_DP + 1];
    #pragma unroll
    for (int k = 0; k <= C_DP; ++k) U[k] = __shfl_up(B[k], 1, 64);
    float Oin = __shfl_up(O, 1, 64);
    if (lane == 0) {
      if (w == 0) {
        #pragma unroll
        for (int k = 0; k <= C_DP; ++k) U[k] = 0.0f;
        U[0] = (c == 0) ? 1.0f : 0.0f;   // E[0][0]=exp(-0)
        Oin = O;
      } else {
        #pragma unroll
        for (int k = 0; k <= C_DP; ++k) U[k] = bnd[p & 1][w - 1][k];
        Oin = bnd[p & 1][w - 1][C_DP + 1];
      }
    }

    bool active = (c >= 0) && (c < NCH);
    if (active) {
      if (c == 0) O = Oin;               // adopt neighbor's frame at activation
      // rescale incoming to own offset (bounded drift after adoption)
      float sc = exp2f((O - Oin) * L2E);
      #pragma unroll
      for (int k = 0; k <= C_DP; ++k) U[k] *= sc;

      #pragma unroll
      for (int r = 0; r < R_DP; ++r) {
        float e[C_DP];
        unpack8(cur[r], e);
        float A[C_DP];
        #pragma unroll
        for (int k = 0; k < C_DP; ++k) A[k] = e[k] * (U[k] + U[k + 1]);
        float oldc = carry[r];
        float left = oldc;
        float V[C_DP];
        #pragma unroll
        for (int k = 0; k < C_DP; ++k) {
          left = fmaf(e[k], left, A[k]);   // E = expd*(Eup+Eupleft+Eleft)
          V[k] = left;
        }
        U[0] = oldc;
        #pragma unroll
        for (int k = 1; k <= C_DP; ++k) U[k] = V[k - 1];
        carry[r] = V[C_DP - 1];
      }

      // renormalize via exponent bits (keeps E ~ 1, updates O)
      float rep = carry[R_DP - 1];
      if (rep > 0.0f) {
        int ex = (int)((__float_as_uint(rep) >> 23) & 0xFF) - 127;
        if ((ex < -18 || ex > 18) && ex < 128) {
          float s = __uint_as_float((unsigned)(127 - ex) << 23);  // 2^-ex
          #pragma unroll
          for (int r = 0; r < R_DP; ++r) carry[r] *= s;
          #pragma unroll
          for (int k = 0; k <= C_DP; ++k) U[k] *= s;
          O -= (float)ex * LN2;          // E *= 2^-ex  =>  O -= ex*ln2
        }
      }
      #pragma unroll
      for (int k = 0; k <= C_DP; ++k) B[k] = U[k];
    }

    // publish wave-boundary state for next phase (frozen B when inactive)
    if (lane == 63) {
      #pragma unroll
      for (int k = 0; k <= C_DP; ++k) bnd[(p + 1) & 1][w][k] = B[k];
      bnd[(p + 1) & 1][w][C_DP + 1] = O;
    }
    __syncthreads();

    #pragma unroll
    for (int r = 0; r < R_DP; ++r) cur[r] = nxt[r];
  }

  if (t == T_DP - 1) out[b] = O - logf(carry[R_DP - 1]);  // R[N][M]
}

// ---------------------------------------------------------------------------
extern "C" void kernel_launch(void* const* d_in, const int* in_sizes, int n_in,
                              void* d_out, int out_size, void* d_ws, size_t ws_size,
                              hipStream_t stream) {
  const float* x = (const float*)d_in[0];
  const float* y = (const float*)d_in[1];
  float* out = (float*)d_out;

  char* ws = (char*)d_ws;
  __half* Dexp = (__half*)ws;
  size_t dd_bytes = (size_t)BATCH * NROW * MCOL * sizeof(__half);  // 33.5 MB
  float* invnx = (float*)(ws + dd_bytes);
  float* invny = invnx + BATCH * NROW;

  norm_kernel<<<(2 * BATCH * NROW) / 4, 256, 0, stream>>>(x, y, invnx, invny);
  dist_kernel<<<dim3(MCOL / 64, NROW / 64, BATCH), 256, 0, stream>>>(
      x, y, invnx, invny, Dexp);
  dtw_kernel<<<BATCH, T_DP, 0, stream>>>(Dexp, out);
}

// Round 6
// 370.182 us; speedup vs baseline: 2.8846x; 1.2903x over previous
//
#include <hip/hip_runtime.h>
#include <hip/hip_fp16.h>

#define BATCH 16
#define NROW 1024
#define MCOL 1024
#define DFEAT 128

// DP blocking
#define T_DP 256            // threads per block (4 waves)
#define R_DP 4              // rows per thread
#define C_DP 8              // columns per phase chunk
#define NCH (MCOL / C_DP)   // 128 chunks along j
#define NPH (NCH + T_DP - 1) // 383 phases

#define L2E 1.4426950408889634f
#define LN2 0.6931471805599453f

typedef __attribute__((ext_vector_type(8))) short short8;
typedef __attribute__((ext_vector_type(4))) float f32x4;

__device__ inline unsigned short f2bf(float f) {  // RNE f32 -> bf16 bits
  unsigned u = __float_as_uint(f);
  return (unsigned short)((u + 0x7fff + ((u >> 16) & 1)) >> 16);
}

// ---------------------------------------------------------------------------
// Kernel 1: normalize rows and emit bf16 copies. One wave per row.
// ---------------------------------------------------------------------------
__global__ __launch_bounds__(256) void norm_kernel(
    const float* __restrict__ x, const float* __restrict__ y,
    unsigned short* __restrict__ xnb, unsigned short* __restrict__ ynb) {
  int row = blockIdx.x * 4 + (threadIdx.x >> 6);
  int lane = threadIdx.x & 63;
  const float* src;
  unsigned short* dst;
  if (row < BATCH * NROW) {
    src = x + (size_t)row * DFEAT;
    dst = xnb + (size_t)row * DFEAT;
  } else {
    int r2 = row - BATCH * NROW;
    src = y + (size_t)r2 * DFEAT;
    dst = ynb + (size_t)r2 * DFEAT;
  }
  float2 v = *(const float2*)(src + lane * 2);
  float s = v.x * v.x + v.y * v.y;
  #pragma unroll
  for (int o = 32; o > 0; o >>= 1) s += __shfl_xor(s, o, 64);
  float inv = 1.0f / (sqrtf(s) + 1e-8f);
  unsigned short b0 = f2bf(v.x * inv), b1 = f2bf(v.y * inv);
  *(unsigned*)(dst + lane * 2) = (unsigned)b0 | ((unsigned)b1 << 16);
}

// ---------------------------------------------------------------------------
// Kernel 2: MFMA distance GEMM, 128x128 tile/block, 4 waves (2x2 of 64x64),
// bf16 16x16x32 MFMA; epilogue stores exp(-(1-dot)) as fp16 row-major.
// LDS XOR-swizzle (byte ^= (row&7)<<4) kills the 16-way LDA bank conflict.
// ---------------------------------------------------------------------------
__global__ __launch_bounds__(256) void dist_kernel(
    const unsigned short* __restrict__ xnb, const unsigned short* __restrict__ ynb,
    __half* __restrict__ Dexp) {
  __shared__ __align__(16) unsigned char xsb[128 * 256];
  __shared__ __align__(16) unsigned char ysb[128 * 256];

  int b = blockIdx.z, ti0 = blockIdx.y, tj0 = blockIdx.x;
  int I0 = ti0 * 128, J0 = tj0 * 128;
  int tid = threadIdx.x;

  const uint4* xsrc = (const uint4*)(xnb + (size_t)(b * NROW + I0) * DFEAT);
  const uint4* ysrc = (const uint4*)(ynb + (size_t)(b * MCOL + J0) * DFEAT);
  #pragma unroll
  for (int it = 0; it < 8; ++it) {
    int idx = tid + it * 256;           // 0..2047: row = idx>>4, 16B col = idx&15
    int row = idx >> 4, cb = (idx & 15) * 16;
    int swz = row * 256 + (cb ^ ((row & 7) << 4));
    *(uint4*)&xsb[swz] = xsrc[idx];
    *(uint4*)&ysb[swz] = ysrc[idx];
  }
  __syncthreads();

  int wid = tid >> 6, lane = tid & 63;
  int wi = wid >> 1, wj = wid & 1;      // 64x64 quadrant
  int lr = lane & 15, lk = lane >> 4;   // frag row/col = lr, k-group = lk

  f32x4 acc[4][4] = {};
  #pragma unroll
  for (int ks = 0; ks < 4; ++ks) {
    int cb = ks * 64 + lk * 16;         // byte col: k0*2 + lk*16
    short8 af[4], bf[4];
    #pragma unroll
    for (int ti = 0; ti < 4; ++ti) {
      int row = wi * 64 + ti * 16 + lr;
      af[ti] = *(short8*)&xsb[row * 256 + (cb ^ ((row & 7) << 4))];
    }
    #pragma unroll
    for (int tj = 0; tj < 4; ++tj) {
      int row = wj * 64 + tj * 16 + lr;
      bf[tj] = *(short8*)&ysb[row * 256 + (cb ^ ((row & 7) << 4))];
    }
    #pragma unroll
    for (int ti = 0; ti < 4; ++ti)
      #pragma unroll
      for (int tj = 0; tj < 4; ++tj)
        acc[ti][tj] = __builtin_amdgcn_mfma_f32_16x16x32_bf16(
            af[ti], bf[tj], acc[ti][tj], 0, 0, 0);
  }

  // epilogue: C/D layout col=lane&15, row=(lane>>4)*4+v  (m89-verified)
  #pragma unroll
  for (int ti = 0; ti < 4; ++ti) {
    #pragma unroll
    for (int tj = 0; tj < 4; ++tj) {
      int gi = I0 + wi * 64 + ti * 16 + lk * 4;
      int gj = J0 + wj * 64 + tj * 16 + lr;
      #pragma unroll
      for (int v = 0; v < 4; ++v) {
        float d = 1.0f - acc[ti][tj][v];
        Dexp[((size_t)b * NROW + gi + v) * MCOL + gj] = __float2half(exp2f(-d * L2E));
      }
    }
  }
}

// ---------------------------------------------------------------------------
// Kernel 3: blocked exp-domain soft-DTW DP (math identical to verified r5).
// Changes: depth-2 prefetch + raw s_barrier WITHOUT vmcnt drain (the
// __syncthreads vmcnt(0) drain serialized the prefetch = 900 cyc/phase).
// ---------------------------------------------------------------------------
__device__ inline void unpack8(uint4 v, float* e) {
  const __half2* h = reinterpret_cast<const __half2*>(&v);
  #pragma unroll
  for (int q = 0; q < 4; ++q) {
    float2 f = __half22float2(h[q]);
    e[2 * q] = f.x;
    e[2 * q + 1] = f.y;
  }
}

__global__ __launch_bounds__(T_DP) void dtw_kernel(
    const __half* __restrict__ Dexp, float* __restrict__ out) {
  int b = blockIdx.x;
  int t = threadIdx.x;
  int lane = t & 63, w = t >> 6;

  __shared__ float bnd[2][T_DP / 64][C_DP + 2];  // [parity][wave][B(9) + O]
  if (t < 2 * (T_DP / 64) * (C_DP + 2)) ((float*)bnd)[t] = 0.0f;
  __syncthreads();

  const __half* Db = Dexp + ((size_t)b * NROW + (size_t)t * R_DP) * MCOL;

  float carry[R_DP] = {0.f, 0.f, 0.f, 0.f};
  float B[C_DP + 1] = {};
  float O = 0.0f;

  auto loadrow = [&](int r, int c) -> uint4 {
    int cc = c < 0 ? 0 : (c >= NCH ? NCH - 1 : c);
    return *reinterpret_cast<const uint4*>(Db + (size_t)r * MCOL + cc * C_DP);
  };

  uint4 cur[R_DP], n1[R_DP], n2[R_DP];
  #pragma unroll
  for (int r = 0; r < R_DP; ++r) cur[r] = loadrow(r, 0 - t);
  #pragma unroll
  for (int r = 0; r < R_DP; ++r) n1[r] = loadrow(r, 1 - t);

  #pragma unroll 3
  for (int p = 0; p < NPH; ++p) {
    int c = p - t;
    // depth-2 prefetch: issue loads for phase p+2
    #pragma unroll
    for (int r = 0; r < R_DP; ++r) n2[r] = loadrow(r, c + 2);

    // receive up-row from neighbor (its B built last phase)
    float U[C_DP + 1];
    #pragma unroll
    for (int k = 0; k <= C_DP; ++k) U[k] = __shfl_up(B[k], 1, 64);
    float Oin = __shfl_up(O, 1, 64);
    if (lane == 0) {
      if (w == 0) {
        #pragma unroll
        for (int k = 0; k <= C_DP; ++k) U[k] = 0.0f;
        U[0] = (c == 0) ? 1.0f : 0.0f;   // E[0][0]=exp(-0)
        Oin = O;
      } else {
        #pragma unroll
        for (int k = 0; k <= C_DP; ++k) U[k] = bnd[p & 1][w - 1][k];
        Oin = bnd[p & 1][w - 1][C_DP + 1];
      }
    }

    bool active = (c >= 0) && (c < NCH);
    if (active) {
      if (c == 0) O = Oin;               // adopt neighbor's frame at activation
      float sc = exp2f((O - Oin) * L2E);
      #pragma unroll
      for (int k = 0; k <= C_DP; ++k) U[k] *= sc;

      #pragma unroll
      for (int r = 0; r < R_DP; ++r) {
        float e[C_DP];
        unpack8(cur[r], e);
        float A[C_DP];
        #pragma unroll
        for (int k = 0; k < C_DP; ++k) A[k] = e[k] * (U[k] + U[k + 1]);
        float oldc = carry[r];
        float left = oldc;
        float V[C_DP];
        #pragma unroll
        for (int k = 0; k < C_DP; ++k) {
          left = fmaf(e[k], left, A[k]);   // E = expd*(Eup+Eupleft+Eleft)
          V[k] = left;
        }
        U[0] = oldc;
        #pragma unroll
        for (int k = 1; k <= C_DP; ++k) U[k] = V[k - 1];
        carry[r] = V[C_DP - 1];
      }

      // renormalize via exponent bits (E *= 2^-ex  =>  O -= ex*ln2)
      float rep = carry[R_DP - 1];
      if (rep > 0.0f) {
        int ex = (int)((__float_as_uint(rep) >> 23) & 0xFF) - 127;
        if ((ex < -18 || ex > 18) && ex < 128) {
          float s = __uint_as_float((unsigned)(127 - ex) << 23);  // 2^-ex
          #pragma unroll
          for (int r = 0; r < R_DP; ++r) carry[r] *= s;
          #pragma unroll
          for (int k = 0; k <= C_DP; ++k) U[k] *= s;
          O -= (float)ex * LN2;
        }
      }
      #pragma unroll
      for (int k = 0; k <= C_DP; ++k) B[k] = U[k];
    }

    // publish wave-boundary state for next phase
    if (lane == 63) {
      #pragma unroll
      for (int k = 0; k <= C_DP; ++k) bnd[(p + 1) & 1][w][k] = B[k];
      bnd[(p + 1) & 1][w][C_DP + 1] = O;
    }
    // raw barrier: drain LDS (lgkm) only — prefetch (vmcnt) stays in flight
    asm volatile("s_waitcnt lgkmcnt(0)" ::: "memory");
    __builtin_amdgcn_s_barrier();

    #pragma unroll
    for (int r = 0; r < R_DP; ++r) { cur[r] = n1[r]; n1[r] = n2[r]; }
  }

  if (t == T_DP - 1) out[b] = O - logf(carry[R_DP - 1]);  // R[N][M]
}

// ---------------------------------------------------------------------------
extern "C" void kernel_launch(void* const* d_in, const int* in_sizes, int n_in,
                              void* d_out, int out_size, void* d_ws, size_t ws_size,
                              hipStream_t stream) {
  const float* x = (const float*)d_in[0];
  const float* y = (const float*)d_in[1];
  float* out = (float*)d_out;

  char* ws = (char*)d_ws;
  __half* Dexp = (__half*)ws;
  size_t dd_bytes = (size_t)BATCH * NROW * MCOL * sizeof(__half);  // 33.5 MB
  unsigned short* xnb = (unsigned short*)(ws + dd_bytes);          // 4 MB
  unsigned short* ynb = xnb + (size_t)BATCH * NROW * DFEAT;        // 4 MB

  norm_kernel<<<(2 * BATCH * NROW) / 4, 256, 0, stream>>>(x, y, xnb, ynb);
  dist_kernel<<<dim3(MCOL / 128, NROW / 128, BATCH), 256, 0, stream>>>(
      xnb, ynb, Dexp);
  dtw_kernel<<<BATCH, T_DP, 0, stream>>>(Dexp, out);
}